// Round 13
// baseline (111.039 us; speedup 1.0000x reference)
//
#include <hip/hip_runtime.h>
#include <math.h>

// EvidNets, fused gemm+combine at 2 blocks/CU + tiny finish kernel.
//   A_c(b) = prod_k (1 - s_kb*(1-U_kc)),  N(b) = prod_k (1 - s_kb)
//   out[b][c<20] = (A_c-N)/K, out[b][20] = N/K, K = sum_c A_c - 19N
//   s_kb = alphap_k * exp(-gamma_k^2*(0.5*(|W_k|^2+|x_b|^2) - W_k.x_b))
// R12 post-mortem: two-kernel split still ~50us of kernel time; gemm at
// 1 block/CU exposed all latency, combine paid its own latency + 32MB S
// round-trip. Now each block covers 64 samples x 256 protos (one LDS pool:
// A-frags 64KB during MFMA, aliased as swizzled s-tile + endgame after),
// 2 blocks/CU co-resident -> one block's combine VALU overlaps the other's
// MFMA. Cross-half partials (2.75MB) merged by `finish`.
// NOTE: plain __launch_bounds__ — min-waves args caused scratch spills (R4/R8).
// VGPR must stay <=128 for 4 waves/SIMD (2 blocks/CU).

#define NBATCH 16384
#define ND     256
#define NP     512
#define NCLS   20
#define OC     21

typedef short  short8  __attribute__((ext_vector_type(8)));
typedef short  short4v __attribute__((ext_vector_type(4)));
typedef unsigned short ushort8 __attribute__((ext_vector_type(8)));
typedef float  f32x16  __attribute__((ext_vector_type(16)));

// ---- workspace layout (bytes) ----
#define OFF_PWH 0u
#define OFF_PWL 262144u
#define OFF_VS  524288u                 // float VS[21][512] = 1-U (row 20 = 1)
#define OFF_WQ  567296u
#define OFF_AP  569344u
#define OFF_G2  571392u
#define OFF_PP  1048576u                // float PP[512][21*64] = 2.75 MB
#define WS_BIG  ((size_t)(OFF_PP + 2752512u))

__device__ __forceinline__ unsigned short f2bf_rn(float f) {
  unsigned int u = __float_as_uint(f);
  unsigned int r = (u + 0x7FFFu + ((u >> 16) & 1u)) >> 16;   // RNE (finite inputs)
  return (unsigned short)r;
}
__device__ __forceinline__ float bf2f(unsigned short h) {
  return __uint_as_float(((unsigned int)h) << 16);
}

// Combined prep: blocks 0..63 pack W[512][256] -> MFMA B-fragment order hi/lo
// bf16 + row sum-squares; blocks 64..65 build VS/AP/G2 tables.
// frag elem (tile,step,lane,j) = src[tile*32+(lane&31)][step*16+8*(lane>>5)+j]
__global__ __launch_bounds__(256)
void prep(const float* __restrict__ Wsrc, const float* __restrict__ BETA,
          const float* __restrict__ alpha, const float* __restrict__ gamma,
          unsigned short* __restrict__ dh, unsigned short* __restrict__ dl,
          float* __restrict__ sq, float* __restrict__ VS,
          float* __restrict__ AP, float* __restrict__ G2)
{
  const int bid = blockIdx.x;
  if (bid < 64) {                      // ---- pack W ----
    const int tid = bid * 256 + threadIdx.x;
    const int row = tid >> 5, seg = tid & 31;
    const float4* s4 = (const float4*)(Wsrc + (size_t)row * ND + seg * 8);
    const float4 a = s4[0], b = s4[1];
    const float v[8] = {a.x, a.y, a.z, a.w, b.x, b.y, b.z, b.w};
    ushort8 hv, lv;
    float ssq = 0.f;
    #pragma unroll
    for (int j = 0; j < 8; ++j) {
      ssq = fmaf(v[j], v[j], ssq);
      const unsigned short hh = f2bf_rn(v[j]);
      hv[j] = hh;
      lv[j] = f2bf_rn(v[j] - bf2f(hh));
    }
    const int tile = row >> 5, m = row & 31, step = seg >> 1, r = seg & 1;
    const size_t cidx = (size_t)(tile * 16 + step) * 64 + m + 32 * r;
    *(ushort8*)(dh + cidx * 8) = hv;
    *(ushort8*)(dl + cidx * 8) = lv;
    #pragma unroll
    for (int off = 1; off < 32; off <<= 1) ssq += __shfl_xor(ssq, off, 64);
    if (seg == 0) sq[row] = ssq;
  } else {                             // ---- scalar tables ----
    const int k = (bid - 64) * 256 + threadIdx.x;
    if (k >= NP) return;
    float bv[NCLS], bs = 0.f;
    #pragma unroll
    for (int c = 0; c < NCLS; ++c) { bv[c] = BETA[k * NCLS + c]; bs = fmaf(bv[c], bv[c], bs); }
    const float binv = 1.f / bs;
    #pragma unroll
    for (int c = 0; c < NCLS; ++c) VS[c * NP + k] = 1.f - bv[c] * bv[c] * binv;
    VS[NCLS * NP + k] = 1.f;
    AP[k] = 0.99f / (1.f + __expf(-alpha[k]));
    const float g = gamma[k];
    G2[k] = g * g;
  }
}

// One MFMA pass over sample-half sh: 32x32 tile, K=256, hi/lo 3 chains,
// epilogue s -> sout[16] (registers).
__device__ __forceinline__ void mfma_pass(
    const short* __restrict__ Ah, const short* __restrict__ Al,
    const short8* __restrict__ bHc, const short8* __restrict__ bLc,
    const int lane, const int sh, const float* __restrict__ xqs,
    const float wqk, const float apk, const float g2k, float* __restrict__ sout)
{
  short8 wbh[4], wbl[4];
  #pragma unroll
  for (int p = 0; p < 4; ++p) { wbh[p] = bHc[p * 64]; wbl[p] = bLc[p * 64]; }

  f32x16 accA, accB, accC;
  #pragma unroll
  for (int i = 0; i < 16; ++i) { accA[i] = 0.f; accB[i] = 0.f; accC[i] = 0.f; }
  const short8* aH = (const short8*)Ah + (size_t)sh * 1024 + lane;
  const short8* aL = (const short8*)Al + (size_t)sh * 1024 + lane;
  #pragma unroll
  for (int step = 0; step < 16; ++step) {
    const short8 ah = aH[step * 64], al = aL[step * 64];
    const short8 bh = wbh[step & 3], bl = wbl[step & 3];
    if (step < 12) {
      wbh[step & 3] = bHc[(step + 4) * 64];
      wbl[step & 3] = bLc[(step + 4) * 64];
    }
    accA = __builtin_amdgcn_mfma_f32_32x32x16_bf16(ah, bh, accA, 0, 0, 0);
    accB = __builtin_amdgcn_mfma_f32_32x32x16_bf16(ah, bl, accB, 0, 0, 0);
    accC = __builtin_amdgcn_mfma_f32_32x32x16_bf16(al, bh, accC, 0, 0, 0);
  }
  // C/D: col(n)=lane&31 (proto), row(m)=(rg&3)+8*(rg>>2)+4*(lane>>5)
  const int h = lane >> 5;
  #pragma unroll
  for (int rg = 0; rg < 16; ++rg) {
    const int   m  = (rg & 3) + 8 * (rg >> 2) + 4 * h;
    const float dv = 0.5f * (wqk + xqs[sh * 32 + m])
                   - (accA[rg] + accB[rg] + accC[rg]);
    sout[rg] = apk * __expf(-g2k * dv);
  }
}

// ---- main: 512 blocks x 512 thr. Block bx: samples (bx>>1)*64..+64,
// protos (bx&1)*256..+256. Wave wv owns 32 protos. LDS pool: A-frags
// (64KB) during MFMA, then swizzled s-tile sc[b][(p+4b)&255], then endgame.
// Writes per-block partial products PP[bx][c*64+b]. ----
__global__ __launch_bounds__(512)
void gemm_comb(const float* __restrict__ X,
               const unsigned short* __restrict__ PWH, const unsigned short* __restrict__ PWL,
               const float* __restrict__ VS, const float* __restrict__ WQ,
               const float* __restrict__ AP, const float* __restrict__ G2,
               float* __restrict__ PP)
{
  __shared__ __align__(16) char pool[65536];
  __shared__ float xqs[64];
  short* Ah = (short*)pool;            // 16384 shorts
  short* Al = (short*)(pool + 32768);  // 16384 shorts
  float* sc = (float*)pool;            // 64 x 256 floats (aliased post-MFMA)

  const int t    = threadIdx.x;
  const int lane = t & 63;
  const int wv   = __builtin_amdgcn_readfirstlane(t >> 6);  // proto wave 0..7
  const int bx   = blockIdx.x;
  const int tile = bx >> 1, half = bx & 1;
  const int bbase = tile * 64;
  const int pl = lane & 31, h = lane >> 5;

  // ---- stage: 64 X rows f32 -> hi/lo bf16 fragments (8 lanes/row) ----
  {
    const int r  = t >> 3;
    const int sg = t & 7;
    const int rsh = r >> 5, rm = r & 31;
    const float* xrow = X + (size_t)(bbase + r) * ND;
    float ssq = 0.f;
    #pragma unroll
    for (int it = 0; it < 8; ++it) {
      const int c0 = it * 32 + sg * 4;
      const float4 v = *(const float4*)(xrow + c0);
      const float vv[4] = {v.x, v.y, v.z, v.w};
      short4v h4, l4;
      #pragma unroll
      for (int j = 0; j < 4; ++j) {
        ssq = fmaf(vv[j], vv[j], ssq);
        const unsigned short hh = f2bf_rn(vv[j]);
        h4[j] = (short)hh;
        l4[j] = (short)f2bf_rn(vv[j] - bf2f(hh));
      }
      const int step = c0 >> 4, hf = (c0 >> 3) & 1, j0 = c0 & 7;
      const int base = (((rsh * 16 + step) * 64) + (rm + 32 * hf)) * 8 + j0;
      *(short4v*)&Ah[base] = h4;
      *(short4v*)&Al[base] = l4;
    }
    ssq += __shfl_xor(ssq, 1, 64);
    ssq += __shfl_xor(ssq, 2, 64);
    ssq += __shfl_xor(ssq, 4, 64);
    if (sg == 0) xqs[r] = ssq;
  }
  __syncthreads();                     // B1: A-frags + xqs ready

  // per-lane prototype params (L2-resident)
  const int kp = half * 256 + wv * 32 + pl;
  const float wqk = WQ[kp], apk = AP[kp], g2k = G2[kp];
  const short8* bHc = (const short8*)PWH + (size_t)(half * 8 + wv) * 1024 + lane;
  const short8* bLc = (const short8*)PWL + (size_t)(half * 8 + wv) * 1024 + lane;

  float sreg0[16], sreg1[16];
  mfma_pass(Ah, Al, bHc, bLc, lane, 0, xqs, wqk, apk, g2k, sreg0);
  mfma_pass(Ah, Al, bHc, bLc, lane, 1, xqs, wqk, apk, g2k, sreg1);

  __syncthreads();                     // B2: all MFMA done, A-frags dead

  // write s-tile: sc[b][(p + 4b) & 255], p = wv*32+pl (conflict-free stores)
  {
    const int p = wv * 32 + pl;
    #pragma unroll
    for (int rg = 0; rg < 16; ++rg) {
      const int m  = (rg & 3) + 8 * (rg >> 2) + 4 * h;
      sc[m * 256 + ((p + 4 * m) & 255)] = sreg0[rg];
      const int b1 = m + 32;
      sc[b1 * 256 + ((p + 4 * b1) & 255)] = sreg1[rg];
    }
  }
  __syncthreads();                     // B3: s-tile complete

  // ---- combine: thread (b = lane, k-slice j3 = wv of 8x32) ----
  float Apc[OC];
  {
    const int j3 = wv;
    float sv[32];
    const int c0 = (j3 * 32 + 4 * lane);
    #pragma unroll
    for (int q = 0; q < 8; ++q)
      *(float4*)&sv[4 * q] = *(const float4*)&sc[lane * 256 + ((c0 + 4 * q) & 255)];

    const float* vt = VS + half * 256 + j3 * 32;   // wave-uniform -> s_load
    for (int c = 0; c < OC; ++c) {
      const float* vp = vt + (size_t)c * NP;
      float f8[8];
      #pragma unroll
      for (int j = 0; j < 8; ++j) f8[j] = fmaf(-sv[j], vp[j], 1.0f);
      #pragma unroll
      for (int j = 8; j < 32; ++j) f8[j & 7] *= fmaf(-sv[j], vp[j], 1.0f);
      Apc[c] = ((f8[0] * f8[1]) * (f8[2] * f8[3])) *
               ((f8[4] * f8[5]) * (f8[6] * f8[7]));
    }
  }
  __syncthreads();                     // B4: sc reads done; pool -> endgame

  // ---- endgame: reduce 8 k-slice partials -> PP[bx][c*64+b] ----
  float* E = (float*)pool;             // 8*21*64 = 10752 floats (42KB)
  #pragma unroll
  for (int c = 0; c < OC; ++c) E[(wv * OC + c) * 64 + lane] = Apc[c];
  __syncthreads();
  {
    const int b = t & 63, j = t >> 6;
    float* pp = PP + (size_t)bx * (OC * 64);
    for (int c = j; c < OC; c += 8) {
      float p = E[c * 64 + b];
      #pragma unroll
      for (int w = 1; w < 8; ++w) p *= E[(w * OC + c) * 64 + b];
      pp[c * 64 + b] = p;
    }
  }
}

// ---- finish: merge the two proto-half partials, normalize, store. ----
__global__ __launch_bounds__(256)
void finish(const float* __restrict__ PP, float* __restrict__ OUT)
{
  const int s = blockIdx.x * 256 + threadIdx.x;   // sample 0..16383
  const int tile = s >> 6, b = s & 63;
  const float* p0 = PP + (size_t)tile * (2 * OC * 64) + b;
  const float* p1 = p0 + OC * 64;
  float A[OC];
  #pragma unroll
  for (int c = 0; c < OC; ++c) A[c] = p0[c * 64] * p1[c * 64];
  const float Nv = A[NCLS];
  float K = Nv;
  #pragma unroll
  for (int c = 0; c < NCLS; ++c) K += A[c] - Nv;
  const float ik = 1.0f / K;
  float* o = OUT + (size_t)s * OC;
  #pragma unroll
  for (int c = 0; c < NCLS; ++c) o[c] = (A[c] - Nv) * ik;
  o[NCLS] = Nv * ik;
}

// ---------------- fallback: R9 fused kernel (proven, used if ws < WS_BIG) ----------------
__global__ __launch_bounds__(512)
void evid_main(const float* __restrict__ X,
               const unsigned short* __restrict__ PWH, const unsigned short* __restrict__ PWL,
               const float* __restrict__ VS, const float* __restrict__ WQ,
               const float* __restrict__ AP, const float* __restrict__ G2,
               float* __restrict__ OUT)
{
  __shared__ __align__(16) short Ah[16384], Al[16384];
  __shared__ __align__(16) float sst[2][8192];
  __shared__ float xqs[64];

  const int t    = threadIdx.x;
  const int lane = t & 63;
  const int wv   = __builtin_amdgcn_readfirstlane(t >> 6);
  const int tile = blockIdx.x;
  const int bbase = tile * 64;
  const int sh = wv & 1, pg = wv >> 1;
  const int pl = lane & 31, h = lane >> 5;

  const short8* bH = (const short8*)PWH + (size_t)pg * 1024 + lane;
  const short8* bL = (const short8*)PWL + (size_t)pg * 1024 + lane;
  short8 wbh[4], wbl[4];
  #pragma unroll
  for (int p = 0; p < 4; ++p) { wbh[p] = bH[p * 64]; wbl[p] = bL[p * 64]; }

  {
    const int r  = t >> 3;
    const int sg = t & 7;
    const int rsh = r >> 5, rm = r & 31;
    const float* xrow = X + (size_t)(bbase + r) * ND;
    float ssq = 0.f;
    #pragma unroll
    for (int it = 0; it < 8; ++it) {
      const int c0 = it * 32 + sg * 4;
      const float4 v = *(const float4*)(xrow + c0);
      const float vv[4] = {v.x, v.y, v.z, v.w};
      short4v h4, l4;
      #pragma unroll
      for (int j = 0; j < 4; ++j) {
        ssq = fmaf(vv[j], vv[j], ssq);
        const unsigned short hh = f2bf_rn(vv[j]);
        h4[j] = (short)hh;
        l4[j] = (short)f2bf_rn(vv[j] - bf2f(hh));
      }
      const int step = c0 >> 4, hf = (c0 >> 3) & 1, j0 = c0 & 7;
      const int base = (((rsh * 16 + step) * 64) + (rm + 32 * hf)) * 8 + j0;
      *(short4v*)&Ah[base] = h4;
      *(short4v*)&Al[base] = l4;
    }
    ssq += __shfl_xor(ssq, 1, 64);
    ssq += __shfl_xor(ssq, 2, 64);
    ssq += __shfl_xor(ssq, 4, 64);
    if (sg == 0) xqs[r] = ssq;
  }
  __syncthreads();

  float xqv[16];
  #pragma unroll
  for (int rg = 0; rg < 16; ++rg)
    xqv[rg] = xqs[sh * 32 + (rg & 3) + 8 * (rg >> 2) + 4 * h];

  float Apc[OC];
  #pragma unroll
  for (int c = 0; c < OC; ++c) Apc[c] = 1.0f;

  #pragma unroll 1
  for (int chunk = 0; chunk < 4; ++chunk) {
    const int par = chunk & 1;
    float* sp = &sst[par][0];
    const int kp = chunk * 128 + pg * 32 + pl;
    const float wqk = WQ[kp], apk = AP[kp], g2k = G2[kp];

    f32x16 accA, accB, accC;
    #pragma unroll
    for (int i = 0; i < 16; ++i) { accA[i] = 0.f; accB[i] = 0.f; accC[i] = 0.f; }
    const short8* aH = (const short8*)Ah + (size_t)sh * 1024 + lane;
    const short8* aL = (const short8*)Al + (size_t)sh * 1024 + lane;
    #pragma unroll
    for (int step = 0; step < 16; ++step) {
      const short8 ah = aH[step * 64], al = aL[step * 64];
      const short8 bh = wbh[step & 3], bl = wbl[step & 3];
      if (step < 12) {
        wbh[step & 3] = bH[(step + 4) * 64];
        wbl[step & 3] = bL[(step + 4) * 64];
      }
      accA = __builtin_amdgcn_mfma_f32_32x32x16_bf16(ah, bh, accA, 0, 0, 0);
      accB = __builtin_amdgcn_mfma_f32_32x32x16_bf16(ah, bl, accB, 0, 0, 0);
      accC = __builtin_amdgcn_mfma_f32_32x32x16_bf16(al, bh, accC, 0, 0, 0);
    }

    #pragma unroll
    for (int rg = 0; rg < 16; ++rg) {
      const int   m  = (rg & 3) + 8 * (rg >> 2) + 4 * h;
      const int   b  = sh * 32 + m;
      const int   col = (pg * 32 + pl + 4 * m) & 127;
      const float dv = 0.5f * (wqk + xqv[rg]) - (accA[rg] + accB[rg] + accC[rg]);
      sp[b * 128 + col] = apk * __expf(-g2k * dv);
    }

    if (chunk < 3) {
      bH += 4096; bL += 4096;
      #pragma unroll
      for (int p = 0; p < 4; ++p) { wbh[p] = bH[p * 64]; wbl[p] = bL[p * 64]; }
    }

    __syncthreads();

    {
      const int kl = wv * 16;
      float sv[16];
      #pragma unroll
      for (int q = 0; q < 4; ++q) {
        const int col = (kl + 4 * (lane & 31) + 4 * q) & 127;
        *(float4*)&sv[4 * q] = *(const float4*)&sp[lane * 128 + col];
      }
      const float* vtab = VS + chunk * 128 + kl;
      for (int c = 0; c < OC; ++c) {
        const float* vp = vtab + (size_t)c * NP;
        float f[16];
        #pragma unroll
        for (int j = 0; j < 16; ++j) f[j] = fmaf(-sv[j], vp[j], 1.0f);
        const float p0 = (f[0] * f[1]) * (f[2] * f[3]);
        const float p1 = (f[4] * f[5]) * (f[6] * f[7]);
        const float p2 = (f[8] * f[9]) * (f[10] * f[11]);
        const float p3 = (f[12] * f[13]) * (f[14] * f[15]);
        Apc[c] *= (p0 * p1) * (p2 * p3);
      }
    }
  }

  __syncthreads();
  float* S = &sst[0][0];
  #pragma unroll
  for (int c = 0; c < OC; ++c) S[(wv * OC + c) * 64 + lane] = Apc[c];
  __syncthreads();
  float* R  = S + 11008;
  {
    const int b = t & 63, j = t >> 6;
    for (int c = j; c < OC; c += 8) {
      float p = S[c * 64 + b];
      #pragma unroll
      for (int w = 1; w < 8; ++w) p *= S[(w * OC + c) * 64 + b];
      R[c * 64 + b] = p;
    }
  }
  __syncthreads();
  float* kv = R + 1344;
  if (t < 64) {
    const float Nv = R[NCLS * 64 + t];
    float K = Nv;
    #pragma unroll
    for (int c = 0; c < NCLS; ++c) K += R[c * 64 + t] - Nv;
    kv[t] = 1.0f / K;
  }
  __syncthreads();
  for (int idx = t; idx < 64 * OC; idx += 512) {
    const int b = idx / OC, c = idx - b * OC;
    const float Nv = R[NCLS * 64 + b];
    const float ik = kv[b];
    OUT[(size_t)tile * 64 * OC + idx] = (c < NCLS) ? (R[c * 64 + b] - Nv) * ik : Nv * ik;
  }
}

extern "C" void kernel_launch(void* const* d_in, const int* in_sizes, int n_in,
                              void* d_out, int out_size, void* d_ws, size_t ws_size,
                              hipStream_t stream) {
  (void)in_sizes; (void)n_in; (void)out_size;
  const float* X     = (const float*)d_in[0];
  const float* Wm    = (const float*)d_in[1];
  const float* BETA  = (const float*)d_in[2];
  const float* ALPHA = (const float*)d_in[3];
  const float* GAMMA = (const float*)d_in[4];
  float* OUT = (float*)d_out;

  char* ws = (char*)d_ws;
  unsigned short* PWH = (unsigned short*)(ws + OFF_PWH);
  unsigned short* PWL = (unsigned short*)(ws + OFF_PWL);
  float* VS = (float*)(ws + OFF_VS);
  float* WQ = (float*)(ws + OFF_WQ);
  float* AP = (float*)(ws + OFF_AP);
  float* G2 = (float*)(ws + OFF_G2);

  hipLaunchKernelGGL(prep, dim3(66), dim3(256), 0, stream,
                     Wm, BETA, ALPHA, GAMMA, PWH, PWL, WQ, VS, AP, G2);

  if (ws_size >= WS_BIG) {
    float* PP = (float*)(ws + OFF_PP);
    hipLaunchKernelGGL(gemm_comb, dim3(NBATCH/32), dim3(512), 0, stream,
                       X, PWH, PWL, VS, WQ, AP, G2, PP);
    hipLaunchKernelGGL(finish, dim3(NBATCH/256), dim3(256), 0, stream,
                       PP, OUT);
  } else {                             // proven fused fallback (R9)
    hipLaunchKernelGGL(evid_main, dim3(NBATCH/64), dim3(512), 0, stream,
                       X, PWH, PWL, VS, WQ, AP, G2, OUT);
  }
}

// Round 14
// 100.734 us; speedup vs baseline: 1.1023x; 1.1023x over previous
//
#include <hip/hip_runtime.h>
#include <math.h>

// EvidNets, fused gemm+combine at 2 blocks/CU + tiny finish kernel.
//   A_c(b) = prod_k (1 - s_kb*(1-U_kc)),  N(b) = prod_k (1 - s_kb)
//   out[b][c<20] = (A_c-N)/K, out[b][20] = N/K, K = sum_c A_c - 19N
//   s_kb = alphap_k * exp(-gamma_k^2*(0.5*(|W_k|^2+|x_b|^2) - W_k.x_b))
// R13 post-mortem: 3 acc chains + 32-reg B ring + sreg0 live across pass 2
// put peak VGPR over the 128 cliff -> 1 block/CU, voiding the co-residency
// premise. Fix: TWO acc chains (cross terms ah*bl and al*bh share accB —
// identical sum, 16 fewer VGPRs) -> peak ~110 <= 128 -> 2 blocks/CU real.
// NOTE: plain __launch_bounds__ — min-waves args caused scratch spills (R4/R8).

#define NBATCH 16384
#define ND     256
#define NP     512
#define NCLS   20
#define OC     21

typedef short  short8  __attribute__((ext_vector_type(8)));
typedef short  short4v __attribute__((ext_vector_type(4)));
typedef unsigned short ushort8 __attribute__((ext_vector_type(8)));
typedef float  f32x16  __attribute__((ext_vector_type(16)));

// ---- workspace layout (bytes) ----
#define OFF_PWH 0u
#define OFF_PWL 262144u
#define OFF_VS  524288u                 // float VS[21][512] = 1-U (row 20 = 1)
#define OFF_WQ  567296u
#define OFF_AP  569344u
#define OFF_G2  571392u
#define OFF_PP  1048576u                // float PP[512][21*64] = 2.75 MB
#define WS_BIG  ((size_t)(OFF_PP + 2752512u))

__device__ __forceinline__ unsigned short f2bf_rn(float f) {
  unsigned int u = __float_as_uint(f);
  unsigned int r = (u + 0x7FFFu + ((u >> 16) & 1u)) >> 16;   // RNE (finite inputs)
  return (unsigned short)r;
}
__device__ __forceinline__ float bf2f(unsigned short h) {
  return __uint_as_float(((unsigned int)h) << 16);
}

// Combined prep: blocks 0..63 pack W[512][256] -> MFMA B-fragment order hi/lo
// bf16 + row sum-squares; blocks 64..65 build VS/AP/G2 tables.
// frag elem (tile,step,lane,j) = src[tile*32+(lane&31)][step*16+8*(lane>>5)+j]
__global__ __launch_bounds__(256)
void prep(const float* __restrict__ Wsrc, const float* __restrict__ BETA,
          const float* __restrict__ alpha, const float* __restrict__ gamma,
          unsigned short* __restrict__ dh, unsigned short* __restrict__ dl,
          float* __restrict__ sq, float* __restrict__ VS,
          float* __restrict__ AP, float* __restrict__ G2)
{
  const int bid = blockIdx.x;
  if (bid < 64) {                      // ---- pack W ----
    const int tid = bid * 256 + threadIdx.x;
    const int row = tid >> 5, seg = tid & 31;
    const float4* s4 = (const float4*)(Wsrc + (size_t)row * ND + seg * 8);
    const float4 a = s4[0], b = s4[1];
    const float v[8] = {a.x, a.y, a.z, a.w, b.x, b.y, b.z, b.w};
    ushort8 hv, lv;
    float ssq = 0.f;
    #pragma unroll
    for (int j = 0; j < 8; ++j) {
      ssq = fmaf(v[j], v[j], ssq);
      const unsigned short hh = f2bf_rn(v[j]);
      hv[j] = hh;
      lv[j] = f2bf_rn(v[j] - bf2f(hh));
    }
    const int tile = row >> 5, m = row & 31, step = seg >> 1, r = seg & 1;
    const size_t cidx = (size_t)(tile * 16 + step) * 64 + m + 32 * r;
    *(ushort8*)(dh + cidx * 8) = hv;
    *(ushort8*)(dl + cidx * 8) = lv;
    #pragma unroll
    for (int off = 1; off < 32; off <<= 1) ssq += __shfl_xor(ssq, off, 64);
    if (seg == 0) sq[row] = ssq;
  } else {                             // ---- scalar tables ----
    const int k = (bid - 64) * 256 + threadIdx.x;
    if (k >= NP) return;
    float bv[NCLS], bs = 0.f;
    #pragma unroll
    for (int c = 0; c < NCLS; ++c) { bv[c] = BETA[k * NCLS + c]; bs = fmaf(bv[c], bv[c], bs); }
    const float binv = 1.f / bs;
    #pragma unroll
    for (int c = 0; c < NCLS; ++c) VS[c * NP + k] = 1.f - bv[c] * bv[c] * binv;
    VS[NCLS * NP + k] = 1.f;
    AP[k] = 0.99f / (1.f + __expf(-alpha[k]));
    const float g = gamma[k];
    G2[k] = g * g;
  }
}

// One MFMA pass over sample-half sh: 32x32 tile, K=256, hi/lo split in TWO
// acc chains (accA = ah*bh; accB = ah*bl + al*bh), epilogue s -> sout[16].
__device__ __forceinline__ void mfma_pass(
    const short* __restrict__ Ah, const short* __restrict__ Al,
    const short8* __restrict__ bHc, const short8* __restrict__ bLc,
    const int lane, const int sh, const float* __restrict__ xqs,
    const float wqk, const float apk, const float g2k, float* __restrict__ sout)
{
  short8 wbh[4], wbl[4];
  #pragma unroll
  for (int p = 0; p < 4; ++p) { wbh[p] = bHc[p * 64]; wbl[p] = bLc[p * 64]; }

  f32x16 accA, accB;
  #pragma unroll
  for (int i = 0; i < 16; ++i) { accA[i] = 0.f; accB[i] = 0.f; }
  const short8* aH = (const short8*)Ah + (size_t)sh * 1024 + lane;
  const short8* aL = (const short8*)Al + (size_t)sh * 1024 + lane;
  #pragma unroll
  for (int step = 0; step < 16; ++step) {
    const short8 ah = aH[step * 64], al = aL[step * 64];
    const short8 bh = wbh[step & 3], bl = wbl[step & 3];
    if (step < 12) {
      wbh[step & 3] = bHc[(step + 4) * 64];
      wbl[step & 3] = bLc[(step + 4) * 64];
    }
    accA = __builtin_amdgcn_mfma_f32_32x32x16_bf16(ah, bh, accA, 0, 0, 0);
    accB = __builtin_amdgcn_mfma_f32_32x32x16_bf16(ah, bl, accB, 0, 0, 0);
    accB = __builtin_amdgcn_mfma_f32_32x32x16_bf16(al, bh, accB, 0, 0, 0);
  }
  // C/D: col(n)=lane&31 (proto), row(m)=(rg&3)+8*(rg>>2)+4*(lane>>5)
  const int h = lane >> 5;
  #pragma unroll
  for (int rg = 0; rg < 16; ++rg) {
    const int   m  = (rg & 3) + 8 * (rg >> 2) + 4 * h;
    const float dv = 0.5f * (wqk + xqs[sh * 32 + m]) - (accA[rg] + accB[rg]);
    sout[rg] = apk * __expf(-g2k * dv);
  }
}

// ---- main: 512 blocks x 512 thr. Block bx: samples (bx>>1)*64..+64,
// protos (bx&1)*256..+256. Wave wv owns 32 protos. LDS pool: A-frags
// (64KB) during MFMA, then swizzled s-tile sc[b][(p+4b)&255], then endgame.
// Writes per-block partial products PP[bx][c*64+b]. ----
__global__ __launch_bounds__(512)
void gemm_comb(const float* __restrict__ X,
               const unsigned short* __restrict__ PWH, const unsigned short* __restrict__ PWL,
               const float* __restrict__ VS, const float* __restrict__ WQ,
               const float* __restrict__ AP, const float* __restrict__ G2,
               float* __restrict__ PP)
{
  __shared__ __align__(16) char pool[65536];
  __shared__ float xqs[64];
  short* Ah = (short*)pool;            // 16384 shorts
  short* Al = (short*)(pool + 32768);  // 16384 shorts
  float* sc = (float*)pool;            // 64 x 256 floats (aliased post-MFMA)

  const int t    = threadIdx.x;
  const int lane = t & 63;
  const int wv   = __builtin_amdgcn_readfirstlane(t >> 6);  // proto wave 0..7
  const int bx   = blockIdx.x;
  const int tile = bx >> 1, half = bx & 1;
  const int bbase = tile * 64;
  const int pl = lane & 31, h = lane >> 5;

  // ---- stage: 64 X rows f32 -> hi/lo bf16 fragments (8 lanes/row) ----
  {
    const int r  = t >> 3;
    const int sg = t & 7;
    const int rsh = r >> 5, rm = r & 31;
    const float* xrow = X + (size_t)(bbase + r) * ND;
    float ssq = 0.f;
    #pragma unroll
    for (int it = 0; it < 8; ++it) {
      const int c0 = it * 32 + sg * 4;
      const float4 v = *(const float4*)(xrow + c0);
      const float vv[4] = {v.x, v.y, v.z, v.w};
      short4v h4, l4;
      #pragma unroll
      for (int j = 0; j < 4; ++j) {
        ssq = fmaf(vv[j], vv[j], ssq);
        const unsigned short hh = f2bf_rn(vv[j]);
        h4[j] = (short)hh;
        l4[j] = (short)f2bf_rn(vv[j] - bf2f(hh));
      }
      const int step = c0 >> 4, hf = (c0 >> 3) & 1, j0 = c0 & 7;
      const int base = (((rsh * 16 + step) * 64) + (rm + 32 * hf)) * 8 + j0;
      *(short4v*)&Ah[base] = h4;
      *(short4v*)&Al[base] = l4;
    }
    ssq += __shfl_xor(ssq, 1, 64);
    ssq += __shfl_xor(ssq, 2, 64);
    ssq += __shfl_xor(ssq, 4, 64);
    if (sg == 0) xqs[r] = ssq;
  }
  __syncthreads();                     // B1: A-frags + xqs ready

  // per-lane prototype params (L2-resident)
  const int kp = half * 256 + wv * 32 + pl;
  const float wqk = WQ[kp], apk = AP[kp], g2k = G2[kp];
  const short8* bHc = (const short8*)PWH + (size_t)(half * 8 + wv) * 1024 + lane;
  const short8* bLc = (const short8*)PWL + (size_t)(half * 8 + wv) * 1024 + lane;

  float sreg0[16], sreg1[16];
  mfma_pass(Ah, Al, bHc, bLc, lane, 0, xqs, wqk, apk, g2k, sreg0);
  mfma_pass(Ah, Al, bHc, bLc, lane, 1, xqs, wqk, apk, g2k, sreg1);

  __syncthreads();                     // B2: all MFMA done, A-frags dead

  // write s-tile: sc[b][(p + 4b) & 255], p = wv*32+pl (conflict-free stores)
  {
    const int p = wv * 32 + pl;
    #pragma unroll
    for (int rg = 0; rg < 16; ++rg) {
      const int m  = (rg & 3) + 8 * (rg >> 2) + 4 * h;
      sc[m * 256 + ((p + 4 * m) & 255)] = sreg0[rg];
      const int b1 = m + 32;
      sc[b1 * 256 + ((p + 4 * b1) & 255)] = sreg1[rg];
    }
  }
  __syncthreads();                     // B3: s-tile complete

  // ---- combine: thread (b = lane, k-slice j3 = wv of 8x32) ----
  float Apc[OC];
  {
    const int j3 = wv;
    float sv[32];
    const int c0 = (j3 * 32 + 4 * lane);
    #pragma unroll
    for (int q = 0; q < 8; ++q)
      *(float4*)&sv[4 * q] = *(const float4*)&sc[lane * 256 + ((c0 + 4 * q) & 255)];

    const float* vt = VS + half * 256 + j3 * 32;   // wave-uniform -> s_load
    for (int c = 0; c < OC; ++c) {
      const float* vp = vt + (size_t)c * NP;
      float f8[8];
      #pragma unroll
      for (int j = 0; j < 8; ++j) f8[j] = fmaf(-sv[j], vp[j], 1.0f);
      #pragma unroll
      for (int j = 8; j < 32; ++j) f8[j & 7] *= fmaf(-sv[j], vp[j], 1.0f);
      Apc[c] = ((f8[0] * f8[1]) * (f8[2] * f8[3])) *
               ((f8[4] * f8[5]) * (f8[6] * f8[7]));
    }
  }
  __syncthreads();                     // B4: sc reads done; pool -> endgame

  // ---- endgame: reduce 8 k-slice partials -> PP[bx][c*64+b] ----
  float* E = (float*)pool;             // 8*21*64 = 10752 floats (42KB)
  #pragma unroll
  for (int c = 0; c < OC; ++c) E[(wv * OC + c) * 64 + lane] = Apc[c];
  __syncthreads();
  {
    const int b = t & 63, j = t >> 6;
    float* pp = PP + (size_t)bx * (OC * 64);
    for (int c = j; c < OC; c += 8) {
      float p = E[c * 64 + b];
      #pragma unroll
      for (int w = 1; w < 8; ++w) p *= E[(w * OC + c) * 64 + b];
      pp[c * 64 + b] = p;
    }
  }
}

// ---- finish: merge the two proto-half partials, normalize, store. ----
__global__ __launch_bounds__(256)
void finish(const float* __restrict__ PP, float* __restrict__ OUT)
{
  const int s = blockIdx.x * 256 + threadIdx.x;   // sample 0..16383
  const int tile = s >> 6, b = s & 63;
  const float* p0 = PP + (size_t)tile * (2 * OC * 64) + b;
  const float* p1 = p0 + OC * 64;
  float A[OC];
  #pragma unroll
  for (int c = 0; c < OC; ++c) A[c] = p0[c * 64] * p1[c * 64];
  const float Nv = A[NCLS];
  float K = Nv;
  #pragma unroll
  for (int c = 0; c < NCLS; ++c) K += A[c] - Nv;
  const float ik = 1.0f / K;
  float* o = OUT + (size_t)s * OC;
  #pragma unroll
  for (int c = 0; c < NCLS; ++c) o[c] = (A[c] - Nv) * ik;
  o[NCLS] = Nv * ik;
}

// ---------------- fallback: R9 fused kernel (proven, used if ws < WS_BIG) ----------------
__global__ __launch_bounds__(512)
void evid_main(const float* __restrict__ X,
               const unsigned short* __restrict__ PWH, const unsigned short* __restrict__ PWL,
               const float* __restrict__ VS, const float* __restrict__ WQ,
               const float* __restrict__ AP, const float* __restrict__ G2,
               float* __restrict__ OUT)
{
  __shared__ __align__(16) short Ah[16384], Al[16384];
  __shared__ __align__(16) float sst[2][8192];
  __shared__ float xqs[64];

  const int t    = threadIdx.x;
  const int lane = t & 63;
  const int wv   = __builtin_amdgcn_readfirstlane(t >> 6);
  const int tile = blockIdx.x;
  const int bbase = tile * 64;
  const int sh = wv & 1, pg = wv >> 1;
  const int pl = lane & 31, h = lane >> 5;

  const short8* bH = (const short8*)PWH + (size_t)pg * 1024 + lane;
  const short8* bL = (const short8*)PWL + (size_t)pg * 1024 + lane;
  short8 wbh[4], wbl[4];
  #pragma unroll
  for (int p = 0; p < 4; ++p) { wbh[p] = bH[p * 64]; wbl[p] = bL[p * 64]; }

  {
    const int r  = t >> 3;
    const int sg = t & 7;
    const int rsh = r >> 5, rm = r & 31;
    const float* xrow = X + (size_t)(bbase + r) * ND;
    float ssq = 0.f;
    #pragma unroll
    for (int it = 0; it < 8; ++it) {
      const int c0 = it * 32 + sg * 4;
      const float4 v = *(const float4*)(xrow + c0);
      const float vv[4] = {v.x, v.y, v.z, v.w};
      short4v h4, l4;
      #pragma unroll
      for (int j = 0; j < 4; ++j) {
        ssq = fmaf(vv[j], vv[j], ssq);
        const unsigned short hh = f2bf_rn(vv[j]);
        h4[j] = (short)hh;
        l4[j] = (short)f2bf_rn(vv[j] - bf2f(hh));
      }
      const int step = c0 >> 4, hf = (c0 >> 3) & 1, j0 = c0 & 7;
      const int base = (((rsh * 16 + step) * 64) + (rm + 32 * hf)) * 8 + j0;
      *(short4v*)&Ah[base] = h4;
      *(short4v*)&Al[base] = l4;
    }
    ssq += __shfl_xor(ssq, 1, 64);
    ssq += __shfl_xor(ssq, 2, 64);
    ssq += __shfl_xor(ssq, 4, 64);
    if (sg == 0) xqs[r] = ssq;
  }
  __syncthreads();

  float xqv[16];
  #pragma unroll
  for (int rg = 0; rg < 16; ++rg)
    xqv[rg] = xqs[sh * 32 + (rg & 3) + 8 * (rg >> 2) + 4 * h];

  float Apc[OC];
  #pragma unroll
  for (int c = 0; c < OC; ++c) Apc[c] = 1.0f;

  #pragma unroll 1
  for (int chunk = 0; chunk < 4; ++chunk) {
    const int par = chunk & 1;
    float* sp = &sst[par][0];
    const int kp = chunk * 128 + pg * 32 + pl;
    const float wqk = WQ[kp], apk = AP[kp], g2k = G2[kp];

    f32x16 accA, accB, accC;
    #pragma unroll
    for (int i = 0; i < 16; ++i) { accA[i] = 0.f; accB[i] = 0.f; accC[i] = 0.f; }
    const short8* aH = (const short8*)Ah + (size_t)sh * 1024 + lane;
    const short8* aL = (const short8*)Al + (size_t)sh * 1024 + lane;
    #pragma unroll
    for (int step = 0; step < 16; ++step) {
      const short8 ah = aH[step * 64], al = aL[step * 64];
      const short8 bh = wbh[step & 3], bl = wbl[step & 3];
      if (step < 12) {
        wbh[step & 3] = bH[(step + 4) * 64];
        wbl[step & 3] = bL[(step + 4) * 64];
      }
      accA = __builtin_amdgcn_mfma_f32_32x32x16_bf16(ah, bh, accA, 0, 0, 0);
      accB = __builtin_amdgcn_mfma_f32_32x32x16_bf16(ah, bl, accB, 0, 0, 0);
      accC = __builtin_amdgcn_mfma_f32_32x32x16_bf16(al, bh, accC, 0, 0, 0);
    }

    #pragma unroll
    for (int rg = 0; rg < 16; ++rg) {
      const int   m  = (rg & 3) + 8 * (rg >> 2) + 4 * h;
      const int   b  = sh * 32 + m;
      const int   col = (pg * 32 + pl + 4 * m) & 127;
      const float dv = 0.5f * (wqk + xqv[rg]) - (accA[rg] + accB[rg] + accC[rg]);
      sp[b * 128 + col] = apk * __expf(-g2k * dv);
    }

    if (chunk < 3) {
      bH += 4096; bL += 4096;
      #pragma unroll
      for (int p = 0; p < 4; ++p) { wbh[p] = bH[p * 64]; wbl[p] = bL[p * 64]; }
    }

    __syncthreads();

    {
      const int kl = wv * 16;
      float sv[16];
      #pragma unroll
      for (int q = 0; q < 4; ++q) {
        const int col = (kl + 4 * (lane & 31) + 4 * q) & 127;
        *(float4*)&sv[4 * q] = *(const float4*)&sp[lane * 128 + col];
      }
      const float* vtab = VS + chunk * 128 + kl;
      for (int c = 0; c < OC; ++c) {
        const float* vp = vtab + (size_t)c * NP;
        float f[16];
        #pragma unroll
        for (int j = 0; j < 16; ++j) f[j] = fmaf(-sv[j], vp[j], 1.0f);
        const float p0 = (f[0] * f[1]) * (f[2] * f[3]);
        const float p1 = (f[4] * f[5]) * (f[6] * f[7]);
        const float p2 = (f[8] * f[9]) * (f[10] * f[11]);
        const float p3 = (f[12] * f[13]) * (f[14] * f[15]);
        Apc[c] *= (p0 * p1) * (p2 * p3);
      }
    }
  }

  __syncthreads();
  float* S = &sst[0][0];
  #pragma unroll
  for (int c = 0; c < OC; ++c) S[(wv * OC + c) * 64 + lane] = Apc[c];
  __syncthreads();
  float* R  = S + 11008;
  {
    const int b = t & 63, j = t >> 6;
    for (int c = j; c < OC; c += 8) {
      float p = S[c * 64 + b];
      #pragma unroll
      for (int w = 1; w < 8; ++w) p *= S[(w * OC + c) * 64 + b];
      R[c * 64 + b] = p;
    }
  }
  __syncthreads();
  float* kv = R + 1344;
  if (t < 64) {
    const float Nv = R[NCLS * 64 + t];
    float K = Nv;
    #pragma unroll
    for (int c = 0; c < NCLS; ++c) K += R[c * 64 + t] - Nv;
    kv[t] = 1.0f / K;
  }
  __syncthreads();
  for (int idx = t; idx < 64 * OC; idx += 512) {
    const int b = idx / OC, c = idx - b * OC;
    const float Nv = R[NCLS * 64 + b];
    const float ik = kv[b];
    OUT[(size_t)tile * 64 * OC + idx] = (c < NCLS) ? (R[c * 64 + b] - Nv) * ik : Nv * ik;
  }
}

extern "C" void kernel_launch(void* const* d_in, const int* in_sizes, int n_in,
                              void* d_out, int out_size, void* d_ws, size_t ws_size,
                              hipStream_t stream) {
  (void)in_sizes; (void)n_in; (void)out_size;
  const float* X     = (const float*)d_in[0];
  const float* Wm    = (const float*)d_in[1];
  const float* BETA  = (const float*)d_in[2];
  const float* ALPHA = (const float*)d_in[3];
  const float* GAMMA = (const float*)d_in[4];
  float* OUT = (float*)d_out;

  char* ws = (char*)d_ws;
  unsigned short* PWH = (unsigned short*)(ws + OFF_PWH);
  unsigned short* PWL = (unsigned short*)(ws + OFF_PWL);
  float* VS = (float*)(ws + OFF_VS);
  float* WQ = (float*)(ws + OFF_WQ);
  float* AP = (float*)(ws + OFF_AP);
  float* G2 = (float*)(ws + OFF_G2);

  hipLaunchKernelGGL(prep, dim3(66), dim3(256), 0, stream,
                     Wm, BETA, ALPHA, GAMMA, PWH, PWL, WQ, VS, AP, G2);

  if (ws_size >= WS_BIG) {
    float* PP = (float*)(ws + OFF_PP);
    hipLaunchKernelGGL(gemm_comb, dim3(NBATCH/32), dim3(512), 0, stream,
                       X, PWH, PWL, VS, WQ, AP, G2, PP);
    hipLaunchKernelGGL(finish, dim3(NBATCH/256), dim3(256), 0, stream,
                       PP, OUT);
  } else {                             // proven fused fallback (R9)
    hipLaunchKernelGGL(evid_main, dim3(NBATCH/64), dim3(512), 0, stream,
                       X, PWH, PWL, VS, WQ, AP, G2, OUT);
  }
}